// Round 1
// baseline (616.252 us; speedup 1.0000x reference)
//
#include <hip/hip_runtime.h>

// Haar DWT (stride-1, non-decimated), depthwise 2x2, right/bottom zero pad.
// x: [B, C, H, W] fp32 -> out: [B, 4*C, H, W] fp32, subband order LL,LH,HL,HH.
//
// Structure: each wave computes a strip of 4 output rows x 256 wide for one
// (b,c) plane, reading 5 input rows ONCE into registers (read amplification
// 1.25x vs 2.0x for 1-row-per-thread). All loads issued up-front for MLP;
// output streamed with nontemporal full-line stores.

typedef float f32x4 __attribute__((ext_vector_type(4)));

constexpr int Bn = 8, Cn = 64, Hn = 256, Wn = 256;
constexpr int ROWS_PER_WAVE   = 4;
constexpr int WAVES_PER_BLOCK = 4;                                // 256 threads
constexpr int ROWS_PER_BLOCK  = ROWS_PER_WAVE * WAVES_PER_BLOCK;  // 16

__global__ __launch_bounds__(256)
void haar_dwt_kernel(const float* __restrict__ x, float* __restrict__ out) {
    const int tid  = threadIdx.x;
    const int lane = tid & 63;        // lane -> j position (4 floats per lane)
    const int wv   = tid >> 6;        // wave within block (0..3)

    const int bc   = blockIdx.y;                                  // b*Cn + c
    const int row0 = blockIdx.x * ROWS_PER_BLOCK + wv * ROWS_PER_WAVE;
    const int j0   = lane * 4;

    const size_t plane_elems = (size_t)Hn * Wn;
    const float* p = x + (size_t)bc * plane_elems + (size_t)row0 * Wn + j0;

    // Load 5 input rows (rows row0 .. row0+4). Only the k=4 row can be
    // out of bounds (bottom zero-pad). Issue everything up-front for MLP.
    f32x4 r[ROWS_PER_WAVE + 1];
    float e[ROWS_PER_WAVE + 1];
    const bool has_e = (j0 + 4 < Wn);   // lane 63 reads zero-pad on the right

#pragma unroll
    for (int k = 0; k < ROWS_PER_WAVE; ++k) {   // always in-bounds (row0+3 <= 255)
        const float* pk = p + k * Wn;
        r[k] = *reinterpret_cast<const f32x4*>(pk);
        e[k] = has_e ? pk[4] : 0.0f;
    }
    {
        const f32x4 zero4 = {0.f, 0.f, 0.f, 0.f};
        f32x4 rl = zero4;
        float el = 0.0f;
        if (row0 + ROWS_PER_WAVE < Hn) {
            const float* pk = p + ROWS_PER_WAVE * Wn;
            rl = *reinterpret_cast<const f32x4*>(pk);
            el = has_e ? pk[4] : 0.0f;
        }
        r[ROWS_PER_WAVE] = rl;
        e[ROWS_PER_WAVE] = el;
    }

    // out channel base: (b*4*Cn + 4*c) == 4*bc
    float* obase = out + (size_t)(4 * bc) * plane_elems + (size_t)row0 * Wn + j0;

#pragma unroll
    for (int i = 0; i < ROWS_PER_WAVE; ++i) {
        const float a0[5] = {r[i][0], r[i][1], r[i][2], r[i][3], e[i]};
        const float a1[5] = {r[i+1][0], r[i+1][1], r[i+1][2], r[i+1][3], e[i+1]};

        f32x4 vll, vlh, vhl, vhh;
#pragma unroll
        for (int k = 0; k < 4; ++k) {
            const float sum0 = a0[k] + a0[k + 1];   // row i   : lo
            const float dif0 = a0[k] - a0[k + 1];   // row i   : hi
            const float sum1 = a1[k] + a1[k + 1];   // row i+1 : lo
            const float dif1 = a1[k] - a1[k + 1];   // row i+1 : hi
            vll[k] = 0.5f * (sum0 + sum1);
            vlh[k] = 0.5f * (sum0 - sum1);
            vhl[k] = 0.5f * (dif0 + dif1);
            vhh[k] = 0.5f * (dif0 - dif1);
        }

        float* orow = obase + i * Wn;
        __builtin_nontemporal_store(vll, reinterpret_cast<f32x4*>(orow));
        __builtin_nontemporal_store(vlh, reinterpret_cast<f32x4*>(orow + plane_elems));
        __builtin_nontemporal_store(vhl, reinterpret_cast<f32x4*>(orow + 2 * plane_elems));
        __builtin_nontemporal_store(vhh, reinterpret_cast<f32x4*>(orow + 3 * plane_elems));
    }
}

extern "C" void kernel_launch(void* const* d_in, const int* in_sizes, int n_in,
                              void* d_out, int out_size, void* d_ws, size_t ws_size,
                              hipStream_t stream) {
    const float* x = (const float*)d_in[0];
    float* out = (float*)d_out;

    dim3 grid(Hn / ROWS_PER_BLOCK, Bn * Cn);   // (16, 512) = 8192 blocks
    haar_dwt_kernel<<<grid, 256, 0, stream>>>(x, out);
}

// Round 2
// 607.104 us; speedup vs baseline: 1.0151x; 1.0151x over previous
//
#include <hip/hip_runtime.h>

// Haar DWT (stride-1, non-decimated), depthwise 2x2, right/bottom zero pad.
// x: [B, C, H, W] fp32 -> out: [B, 4*C, H, W] fp32, subband LL,LH,HL,HH.
//
// Grid-stride, software-pipelined: 2048 blocks x 256 thr (8 blocks/CU,
// full 32-wave occupancy), 16 iterations/thread. Each wave owns one full
// 256-wide row per iteration (lane = j-segment), walking 32 planes per
// step so row/lane/predicates are loop-invariant -- per-iteration state
// update is two pointer bumps. Next iteration's loads issue BEFORE the
// current iteration's compute+stores (always >=2 loads in flight/wave).
// Neighbor column via __shfl_down instead of a second scalar load.

typedef float f32x4 __attribute__((ext_vector_type(4)));

constexpr int Bn = 8, Cn = 64, Hn = 256, Wn = 256;
constexpr int TPB    = 256;
constexpr int BLOCKS = 2048;
constexpr int PLANE  = Hn * Wn;                                // 65536
constexpr int TOTAL_THREADS = BLOCKS * TPB;                    // 524288
constexpr int ITEMS  = Bn * Cn * Hn * (Wn / 4);                // 8388608
constexpr int ITERS  = ITEMS / TOTAL_THREADS;                  // 16
constexpr int BC_STRIDE = TOTAL_THREADS / (Hn * (Wn / 4));     // 32 planes/iter

__global__ __launch_bounds__(TPB)
void haar_dwt_kernel(const float* __restrict__ x, float* __restrict__ out) {
    const int g    = blockIdx.x * TPB + threadIdx.x;
    const int lane = threadIdx.x & 63;
    const int row  = (g >> 6) & (Hn - 1);   // loop-invariant
    const int bc0  = g >> 14;               // starting plane [0,32)
    const int j0   = (g & 63) * 4;          // lane*4, loop-invariant

    const bool has_row1 = (row + 1 < Hn);   // wave-uniform, loop-invariant
    const bool has_e    = (lane != 63);     // loop-invariant

    const float* p = x   + (size_t)bc0 * PLANE       + (size_t)row * Wn + j0;
    float*       o = out + (size_t)(4 * bc0) * PLANE + (size_t)row * Wn + j0;

    const size_t in_step  = (size_t)BC_STRIDE * PLANE;       // 2M floats
    const size_t out_step = (size_t)BC_STRIDE * 4 * PLANE;   // 8M floats

    // Prologue: loads for iteration 0.
    f32x4 r0 = *reinterpret_cast<const f32x4*>(p);
    f32x4 r1 = {0.f, 0.f, 0.f, 0.f};
    if (has_row1) r1 = *reinterpret_cast<const f32x4*>(p + Wn);

    for (int it = 0; it < ITERS; ++it) {
        // Issue next iteration's loads first (stay in flight across the
        // compute + stores below).
        const float* pn = p + in_step;
        f32x4 n0 = {0.f, 0.f, 0.f, 0.f};
        f32x4 n1 = {0.f, 0.f, 0.f, 0.f};
        if (it + 1 < ITERS) {
            n0 = *reinterpret_cast<const f32x4*>(pn);
            if (has_row1) n1 = *reinterpret_cast<const f32x4*>(pn + Wn);
        }

        // Neighbor column x[row][j0+4] = lane+1's r[0]. All lanes run the
        // shuffle (convergent); lane 63 masks to the right zero-pad.
        const float t0 = __shfl_down(r0[0], 1);
        const float t1 = __shfl_down(r1[0], 1);
        const float e0 = has_e ? t0 : 0.0f;
        const float e1 = has_e ? t1 : 0.0f;

        const float a0[5] = {r0[0], r0[1], r0[2], r0[3], e0};
        const float a1[5] = {r1[0], r1[1], r1[2], r1[3], e1};

        f32x4 vll, vlh, vhl, vhh;
#pragma unroll
        for (int k = 0; k < 4; ++k) {
            const float sum0 = a0[k] + a0[k + 1];   // row i   : lo
            const float dif0 = a0[k] - a0[k + 1];   // row i   : hi
            const float sum1 = a1[k] + a1[k + 1];   // row i+1 : lo
            const float dif1 = a1[k] - a1[k + 1];   // row i+1 : hi
            vll[k] = 0.5f * (sum0 + sum1);
            vlh[k] = 0.5f * (sum0 - sum1);
            vhl[k] = 0.5f * (dif0 + dif1);
            vhh[k] = 0.5f * (dif0 - dif1);
        }

        *reinterpret_cast<f32x4*>(o)             = vll;
        *reinterpret_cast<f32x4*>(o + PLANE)     = vlh;
        *reinterpret_cast<f32x4*>(o + 2 * PLANE) = vhl;
        *reinterpret_cast<f32x4*>(o + 3 * PLANE) = vhh;

        p = pn;
        o += out_step;
        r0 = n0;
        r1 = n1;
    }
}

extern "C" void kernel_launch(void* const* d_in, const int* in_sizes, int n_in,
                              void* d_out, int out_size, void* d_ws, size_t ws_size,
                              hipStream_t stream) {
    const float* x = (const float*)d_in[0];
    float* out = (float*)d_out;

    haar_dwt_kernel<<<BLOCKS, TPB, 0, stream>>>(x, out);
}